// Round 22
// baseline (3713.369 us; speedup 1.0000x reference)
//
#include <hip/hip_runtime.h>
#include <hip/hip_fp8.h>

#define NB 1024
#define SL 300
#define NT 150
#define NH 256
#define LA 320
#define NV 81
#define HST 272   // f16 row stride in halves: 136 words ≡ 8 (mod 32)
#define BST 288   // fp8 row stride in bytes: 72 words ≡ 8 (mod 32)

typedef _Float16 f16;
typedef _Float16 f16x2 __attribute__((ext_vector_type(2)));
typedef _Float16 f16x8 __attribute__((ext_vector_type(8)));
typedef float    f32x4 __attribute__((ext_vector_type(4)));

// ws float offsets (bytes-vs-floats audited)
#define OFF_WATT    0u         // [512][320] f32 (163840)
#define OFF_WCOMBT  163840u    // [512][256] f32 (131072)
#define OFF_P1B     294912u    // [81][320] f32 (25920)
#define OFF_P2B     320832u    // [81][256] f32 (20736)
#define OFF_Q2T     341568u    // [81][256] f32 intermediate (20736)
#define OFF_Q2PE    362304u    // [256]
#define OFF_PE      362560u    // [256]
#define OFF_Q2TM    362816u    // f16 frags [16 nt][3 kw][64][8] = 24576 halves (12288 floats)
#define OFF_WCAT8   375104u    // fp8 frags [64 nt][16 kw][64][8] = 524288 B (131072 floats)
#define OFF_WATTM   506176u    // f16 frags [20 nt][8 kw][64][8] = 81920 halves (40960 floats)
#define OFF_WFCM    547136u    // f16 frags [6 nt][8 kw][64][8] = 24576 halves (12288 floats)
#define OFF_LOSS    559424u    // [1024]

static __device__ __forceinline__ float rcpf(float x)  { return __builtin_amdgcn_rcpf(x); }
static __device__ __forceinline__ float sigm(float x)  { return rcpf(1.f + __expf(-x)); }
static __device__ __forceinline__ float tanhf_(float x){ return 1.f - 2.f * rcpf(1.f + __expf(2.f * x)); }

static __device__ __forceinline__ unsigned char f2fp8(float x) {
#if __has_builtin(__builtin_amdgcn_cvt_pk_fp8_f32)
    return (unsigned char)(__builtin_amdgcn_cvt_pk_fp8_f32(x, 0.f, 0, false) & 0xff);
#else
    __hip_fp8_e4m3 t(x);
    return (unsigned char)t.__x;
#endif
}

// ---------------- setup kernels ----------------
__global__ __launch_bounds__(128) void k_pe(float* __restrict__ pe) {
    const int i = threadIdx.x;
    const float arg  = (float)(2 * i) * (-0.035977892078031968f);
    const float divf = expf(arg) * 300.0f;
    pe[2 * i]     = (float)sin((double)divf);
    pe[2 * i + 1] = (float)cos((double)divf);
}
__global__ __launch_bounds__(256) void k_tr_att(const float* __restrict__ W, float* __restrict__ WT) {
    const int i = blockIdx.x * 256 + threadIdx.x;
    if (i < 512 * LA) { const int k = i / LA, l = i - k * LA; WT[i] = W[l * 512 + k]; }
}
__global__ __launch_bounds__(256) void k_tr_comb(const float* __restrict__ W, float* __restrict__ WT) {
    const int i = blockIdx.x * 256 + threadIdx.x;
    const int k = i >> 8, j = i & 255;
    if (i < 512 * NH) WT[i] = W[j * 512 + k];
}
__global__ __launch_bounds__(320) void k_p1b(const float* __restrict__ emb, const float* __restrict__ WATT,
                                             const float* __restrict__ b_att, float* __restrict__ P1B) {
    __shared__ float e[NH];
    const int v = blockIdx.x, tid = threadIdx.x;
    if (tid < NH) e[tid] = emb[v * NH + tid];
    __syncthreads();
    float a = b_att[tid];
    #pragma unroll 8
    for (int k = 0; k < NH; ++k) a += e[k] * WATT[k * LA + tid];
    P1B[v * LA + tid] = a;
}
__global__ __launch_bounds__(256) void k_p2q(const float* __restrict__ emb, const float* __restrict__ WCOMBT,
                                             const float* __restrict__ b_comb,
                                             float* __restrict__ P2B, float* __restrict__ Q2T) {
    __shared__ float e[NH];
    const int v = blockIdx.x, tid = threadIdx.x;
    e[tid] = emb[v * NH + tid];
    __syncthreads();
    float a = b_comb[tid], q = 0.f;
    #pragma unroll 8
    for (int k = 0; k < NH; ++k) {
        a += e[k] * WCOMBT[k * NH + tid];
        q += e[k] * WCOMBT[(NH + k) * NH + tid];
    }
    P2B[v * NH + tid] = a;
    Q2T[v * NH + tid] = q;
}
__global__ __launch_bounds__(256) void k_q2pe(const float* __restrict__ pe, const float* __restrict__ WCOMBT,
                                              float* __restrict__ Q2PE) {
    __shared__ float e[NH];
    const int tid = threadIdx.x;
    e[tid] = pe[tid];
    __syncthreads();
    float q = 0.f;
    #pragma unroll 8
    for (int k = 0; k < NH; ++k) q += e[k] * WCOMBT[(NH + k) * NH + tid];
    Q2PE[tid] = q;
}
// Q2T -> f16 MFMA B-frags: B[k=v (pad 96)][col=j]
__global__ __launch_bounds__(256) void k_pan_q2m(const float* __restrict__ Q2T, f16* __restrict__ P) {
    const int i = blockIdx.x * 256 + threadIdx.x;
    if (i < 96 * 256) {
        const int v = i >> 8, j = i & 255;
        const float val = (v < NV) ? Q2T[v * NH + j] : 0.f;
        const int nt = j >> 4, kw = v >> 5, kr = v & 31;
        const int l = (kr >> 3) * 16 + (j & 15), jj = kr & 7;
        P[nt * 1536 + kw * 512 + l * 8 + jj] = (f16)val;
    }
}
// gates weights -> fp8 MFMA B-frags, stored e4m3(64*w)
__global__ __launch_bounds__(256) void k_pan_cat_8(const float* __restrict__ Wih, const float* __restrict__ Whh,
                                                   unsigned char* __restrict__ P) {
    const int i = blockIdx.x * 256 + threadIdx.x;
    if (i < 512 * 1024) {
        const int k = i >> 10, c = i & 1023, jcol = c >> 2, g = c & 3;
        const float v = (k < NH) ? Wih[(g * NH + jcol) * NH + k] : Whh[(g * NH + jcol) * NH + (k - NH)];
        const int nt = c >> 4, kw = k >> 5, kr = k & 31;
        const int l = (kr >> 3) * 16 + (c & 15), jj = kr & 7;
        P[nt * 8192 + kw * 512 + l * 8 + jj] = f2fp8(v * 64.f);
    }
}
// attn-h weights -> f16 MFMA B-frags
__global__ __launch_bounds__(256) void k_pan_att_m(const float* __restrict__ W, f16* __restrict__ P) {
    const int i = blockIdx.x * 256 + threadIdx.x;
    if (i < 256 * LA) {
        const int k = i / LA, lcol = i - k * LA;
        const float v = W[lcol * 512 + 256 + k];
        const int nt = lcol >> 4, kw = k >> 5, kr = k & 31;
        const int l = (kr >> 3) * 16 + (lcol & 15), jj = kr & 7;
        P[nt * 4096 + kw * 512 + l * 8 + jj] = (f16)v;
    }
}
// W_fc -> f16 MFMA B-frags (pad 81->96 cols)
__global__ __launch_bounds__(256) void k_pan_fc_m(const float* __restrict__ W, f16* __restrict__ P) {
    const int i = blockIdx.x * 256 + threadIdx.x;
    if (i < 256 * 96) {
        const int k = i / 96, v = i - k * 96;
        const float val = (v < NV) ? W[v * NH + k] : 0.f;
        const int nt = v >> 4, kw = k >> 5, kr = k & 31;
        const int l = (kr >> 3) * 16 + (v & 15), jj = kr & 7;
        P[nt * 4096 + kw * 512 + l * 8 + jj] = (f16)val;
    }
}

// ---------------- persistent decoder: 256 blocks x 1024 threads, 4 rows/block ----------------
__global__ __launch_bounds__(1024, 4) void k_run(
    const int* __restrict__ enc, const int* __restrict__ tgt,
    const f16* __restrict__ WATTM, const float* __restrict__ P1B,
    const float* __restrict__ P2B, const f16* __restrict__ Q2TM,
    const float* __restrict__ Q2PE, const unsigned char* __restrict__ WCAT8,
    const f16* __restrict__ WFCM,
    const float* __restrict__ bih, const float* __restrict__ bhh,
    const float* __restrict__ bfc, float* __restrict__ out_logits,
    float* __restrict__ loss_out)
{
    __shared__ __attribute__((aligned(16))) f16 hbufh[2][4][HST];
    __shared__ __attribute__((aligned(16))) unsigned char hb8[2][4][BST];
    __shared__ __attribute__((aligned(16))) unsigned char xh8[4][BST];
    __shared__ __attribute__((aligned(16))) f16 q2m_lds[16 * 1536];   // 48 KB
    __shared__ __attribute__((aligned(16))) f16 cwh[4][96];
    __shared__ float q2pe_lds[NH];
    __shared__ float p_s[4][324];
    __shared__ float gex[4][1024];
    __shared__ float bsum_lds[1024];
    __shared__ float lg_s[4][96];
    __shared__ unsigned short idx16[4][SL];
    __shared__ unsigned short cnt16[4][NV];
    __shared__ unsigned short offs16[4][NV + 1];
    __shared__ float sm_inv[4], sm_s300[4];
    __shared__ float bfc_s[96];
    __shared__ float loss_s[4];
    __shared__ int   xd_s[4];

    const int tid  = threadIdx.x;
    const int rowg = tid >> 8;
    const int jg   = tid & 255;
    const int wid  = tid >> 6;
    const int lane = tid & 63;
    const int mrow = lane & 15;
    const int arow4 = mrow & 3;
    const int khi  = lane >> 4;
    const int row0 = blockIdx.x * 4;
    // gates ntile assignment: waves 0-3 -> 1 nt (= wid); waves 4-15 -> 5 nt from nt0g
    const int nt0g = (wid < 4) ? wid : (4 + (wid - 4) * 5);

    // ---- init ----
    {
        f16* hz = &hbufh[0][0][0];
        for (int i = tid; i < 2 * 4 * HST; i += 1024) hz[i] = (f16)0.f;
        unsigned char* h8 = &hb8[0][0][0];
        for (int i = tid; i < 2 * 4 * BST; i += 1024) h8[i] = 0;
        unsigned char* x8 = &xh8[0][0];
        for (int i = tid; i < 4 * BST; i += 1024) x8[i] = 0;
    }
    { const int j = tid >> 2, g = tid & 3; bsum_lds[tid] = bih[g * NH + j] + bhh[g * NH + j]; }
    if (tid < 96) bfc_s[tid] = (tid < NV) ? bfc[tid] : 0.f;
    if (tid < 4 * 96) cwh[tid / 96][tid % 96] = (f16)0.f;
    if (tid < 4) { xd_s[tid] = 1; loss_s[tid] = 0.f; }
    for (int i = tid; i < 3072; i += 1024)
        ((f16x8*)q2m_lds)[i] = ((const f16x8*)Q2TM)[i];
    if (tid < NH) q2pe_lds[tid] = Q2PE[tid];
    const int* __restrict__ encr = enc + (row0 + rowg) * SL;
    if (jg < NV) {
        int c = 0;
        for (int l = 0; l < SL; ++l) c += (encr[l] == jg);
        cnt16[rowg][jg] = (unsigned short)c;
    }
    __syncthreads();
    if (jg == 0) {
        int o = 0; offs16[rowg][0] = 0;
        for (int v = 0; v < NV; ++v) { o += cnt16[rowg][v]; offs16[rowg][v + 1] = (unsigned short)o; }
    }
    __syncthreads();
    if (jg < NV) {
        int o = offs16[rowg][jg];
        for (int l = 0; l < SL; ++l) if (encr[l] == jg) idx16[rowg][o++] = (unsigned short)l;
    }
    __syncthreads();

    // ---- prologue: P1(0) on all 16 waves (h = 0) ----
    {
        f32x4 za0 = {0.f, 0.f, 0.f, 0.f}, za1 = {0.f, 0.f, 0.f, 0.f};
        const bool two = (wid < 4);
        const f16* __restrict__ B0 = WATTM + wid * 4096 + lane * 8;
        const f16* __restrict__ B1 = WATTM + (16 + wid) * 4096 + lane * 8;
        const f16* __restrict__ hr = &hbufh[0][arow4][khi * 8];
        #pragma unroll 4
        for (int kw = 0; kw < 8; ++kw) {
            const f16x8 a = *(const f16x8*)(hr + kw * 32);
            za0 = __builtin_amdgcn_mfma_f32_16x16x32_f16(a, *(const f16x8*)(B0 + kw * 512), za0, 0, 0, 0);
            if (two)
                za1 = __builtin_amdgcn_mfma_f32_16x16x32_f16(a, *(const f16x8*)(B1 + kw * 512), za1, 0, 0, 0);
        }
        if (lane < 16) {
            #pragma unroll
            for (int i = 0; i < 4; ++i) p_s[i][wid * 16 + mrow] = za0[i];
            if (two) {
                #pragma unroll
                for (int i = 0; i < 4; ++i) p_s[i][256 + wid * 16 + mrow] = za1[i];
            }
        }
    }
    __syncthreads();

    float creg = 0.f;   // cell state for (rowg, jg)

    for (int t = 0; t < NT; ++t) {
        const int pb = t & 1;
        f32x4 gacc[5];
        #pragma unroll
        for (int n = 0; n < 5; ++n) gacc[n] = (f32x4){0.f, 0.f, 0.f, 0.f};

        // ---- unconditional named-scalar prefetch: x-half of first gates ntile (8 frags) ----
        const unsigned char* __restrict__ BGp = WCAT8 + (size_t)nt0g * 8192 + lane * 8;
        const long p0 = *(const long*)(BGp);
        const long p1 = *(const long*)(BGp + 512);
        const long p2 = *(const long*)(BGp + 1024);
        const long p3 = *(const long*)(BGp + 1536);
        const long p4 = *(const long*)(BGp + 2048);
        const long p5 = *(const long*)(BGp + 2560);
        const long p6 = *(const long*)(BGp + 3072);
        const long p7 = *(const long*)(BGp + 3584);

        // ---- window W2: waves 0-3 softmax+binning(t); waves 4-15 gates h-half(t) ----
        if (wid < 4) {
            const int r = wid;
            const float* __restrict__ P1r = P1B + xd_s[r] * LA;
            float zv[5];
            #pragma unroll
            for (int i = 0; i < 5; ++i) zv[i] = p_s[r][lane + 64 * i] + P1r[lane + 64 * i];
            float m = fmaxf(fmaxf(fmaxf(zv[0], zv[1]), fmaxf(zv[2], zv[3])), zv[4]);
            #pragma unroll
            for (int off = 32; off > 0; off >>= 1) m = fmaxf(m, __shfl_xor(m, off));
            float sa = 0.f;
            #pragma unroll
            for (int i = 0; i < 5; ++i) {
                zv[i] = __expf(zv[i] - m);
                p_s[r][lane + 64 * i] = zv[i];
                sa += zv[i];
            }
            float sh = (lane >= 44) ? zv[4] : 0.f;         // l in [300,320)
            #pragma unroll
            for (int off = 32; off > 0; off >>= 1) { sa += __shfl_xor(sa, off); sh += __shfl_xor(sh, off); }
            {   // bins 0..63
                const int o0 = offs16[r][lane], o1 = offs16[r][lane + 1];
                float s = 0.f;
                for (int o = o0; o < o1; ++o) s += p_s[r][idx16[r][o]];
                cwh[r][lane] = (f16)s;
            }
            if (lane < NV - 64) {   // bins 64..80
                const int b2 = 64 + lane;
                const int o0 = offs16[r][b2], o1 = offs16[r][b2 + 1];
                float s = 0.f;
                for (int o = o0; o < o1; ++o) s += p_s[r][idx16[r][o]];
                cwh[r][b2] = (f16)s;
            }
            if (lane == 0) { sm_inv[r] = 1.0f / sa; sm_s300[r] = sa - sh; }
        } else {
            // gates h-half: 5 ntiles, kw 8..15 (A = h(t) fp8, ready since t-1's B7)
            const unsigned char* __restrict__ BG = WCAT8 + (size_t)nt0g * 8192 + lane * 8;
            const unsigned char* __restrict__ hr8 = &hb8[pb][arow4][khi * 8];
            #pragma unroll 2
            for (int kw = 8; kw < 16; ++kw) {
                const long a = *(const long*)(hr8 + (kw - 8) * 32);
                const unsigned char* bp = BG + kw * 512;
                #pragma unroll
                for (int n = 0; n < 5; ++n)
                    gacc[n] = __builtin_amdgcn_mfma_f32_16x16x32_fp8_fp8(
                        a, *(const long*)(bp + (size_t)n * 8192), gacc[n], 0, 0, 0);
            }
        }
        __syncthreads();                                   // B3

        // ---- phase 2: x via MFMA (wave = 1 ntile of 16 cols; K=96) + epilogue ----
        {
            f32x4 xacc = {0.f, 0.f, 0.f, 0.f};
            const f16* __restrict__ Aq = &cwh[arow4][khi * 8];
            const f16* __restrict__ Bq = q2m_lds + wid * 1536 + lane * 8;
            #pragma unroll
            for (int kw = 0; kw < 3; ++kw) {
                const f16x8 a = *(const f16x8*)(Aq + kw * 32);
                const f16x8 b = *(const f16x8*)(Bq + kw * 512);
                xacc = __builtin_amdgcn_mfma_f32_16x16x32_f16(a, b, xacc, 0, 0, 0);
            }
            if (lane < 16) {
                const int col = wid * 16 + mrow;
                #pragma unroll
                for (int i = 0; i < 4; ++i) {
                    const float xval = fmaxf(P2B[xd_s[i] * NH + col]
                                             + (xacc[i] + sm_s300[i] * q2pe_lds[col]) * sm_inv[i], 0.f);
                    xh8[i][col] = f2fp8(xval * 16.f);
                }
            }
        }
        __syncthreads();                                   // B5

        // ---- phase 3: gates completion (first ntile x-half from p0..p7) ----
#define XA(kk) (*(const long*)(xr8 + (kk) * 32))
        if (wid < 4) {
            const unsigned char* __restrict__ BG = WCAT8 + (size_t)nt0g * 8192 + lane * 8;
            const unsigned char* __restrict__ xr8 = &xh8[arow4][khi * 8];
            const unsigned char* __restrict__ hr8 = &hb8[pb][arow4][khi * 8];
            gacc[0] = __builtin_amdgcn_mfma_f32_16x16x32_fp8_fp8(XA(0), p0, gacc[0], 0, 0, 0);
            gacc[0] = __builtin_amdgcn_mfma_f32_16x16x32_fp8_fp8(XA(1), p1, gacc[0], 0, 0, 0);
            gacc[0] = __builtin_amdgcn_mfma_f32_16x16x32_fp8_fp8(XA(2), p2, gacc[0], 0, 0, 0);
            gacc[0] = __builtin_amdgcn_mfma_f32_16x16x32_fp8_fp8(XA(3), p3, gacc[0], 0, 0, 0);
            gacc[0] = __builtin_amdgcn_mfma_f32_16x16x32_fp8_fp8(XA(4), p4, gacc[0], 0, 0, 0);
            gacc[0] = __builtin_amdgcn_mfma_f32_16x16x32_fp8_fp8(XA(5), p5, gacc[0], 0, 0, 0);
            gacc[0] = __builtin_amdgcn_mfma_f32_16x16x32_fp8_fp8(XA(6), p6, gacc[0], 0, 0, 0);
            gacc[0] = __builtin_amdgcn_mfma_f32_16x16x32_fp8_fp8(XA(7), p7, gacc[0], 0, 0, 0);
            #pragma unroll 4
            for (int kw = 8; kw < 16; ++kw) {
                const long a = *(const long*)(hr8 + (kw - 8) * 32);
                gacc[0] = __builtin_amdgcn_mfma_f32_16x16x32_fp8_fp8(
                    a, *(const long*)(BG + kw * 512), gacc[0], 0, 0, 0);
            }
            if (lane < 16) {
                const int cc = nt0g * 16 + mrow;
                #pragma unroll
                for (int i = 0; i < 4; ++i) gex[i][cc] = gacc[0][i] * 0.0009765625f;
            }
        } else {
            const unsigned char* __restrict__ BG = WCAT8 + (size_t)nt0g * 8192 + lane * 8;
            const unsigned char* __restrict__ xr8 = &xh8[arow4][khi * 8];
            // ntile 0 from prefetched p0..p7; ntiles 1-4 from memory
#define PH3STEP(kk, pk) { \
            const long a = XA(kk); \
            gacc[0] = __builtin_amdgcn_mfma_f32_16x16x32_fp8_fp8(a, pk, gacc[0], 0, 0, 0); \
            gacc[1] = __builtin_amdgcn_mfma_f32_16x16x32_fp8_fp8(a, *(const long*)(BG + 1 * 8192 + (kk) * 512), gacc[1], 0, 0, 0); \
            gacc[2] = __builtin_amdgcn_mfma_f32_16x16x32_fp8_fp8(a, *(const long*)(BG + 2 * 8192 + (kk) * 512), gacc[2], 0, 0, 0); \
            gacc[3] = __builtin_amdgcn_mfma_f32_16x16x32_fp8_fp8(a, *(const long*)(BG + 3 * 8192 + (kk) * 512), gacc[3], 0, 0, 0); \
            gacc[4] = __builtin_amdgcn_mfma_f32_16x16x32_fp8_fp8(a, *(const long*)(BG + 4 * 8192 + (kk) * 512), gacc[4], 0, 0, 0); }
            PH3STEP(0, p0) PH3STEP(1, p1) PH3STEP(2, p2) PH3STEP(3, p3)
            PH3STEP(4, p4) PH3STEP(5, p5) PH3STEP(6, p6) PH3STEP(7, p7)
#undef PH3STEP
            if (lane < 16) {
                #pragma unroll
                for (int n = 0; n < 5; ++n) {
                    const int cc = (nt0g + n) * 16 + mrow;
                    #pragma unroll
                    for (int i = 0; i < 4; ++i) gex[i][cc] = gacc[n][i] * 0.0009765625f;
                }
            }
        }
#undef XA
        __syncthreads();                                   // B6

        // ---- LSTM pointwise (adds bias); writes h f16 + fp8 ----
        {
            const float4 g4 = *(const float4*)(gex[rowg] + 4 * jg);   // i,f,g,o
            const float4 b4 = *(const float4*)(bsum_lds + 4 * jg);
            creg = sigm(g4.y + b4.y) * creg + sigm(g4.x + b4.x) * tanhf_(g4.z + b4.z);
            const float hv = sigm(g4.w + b4.w) * tanhf_(creg);
            hbufh[pb ^ 1][rowg][jg] = (f16)hv;
            hb8[pb ^ 1][rowg][jg] = f2fp8(hv * 16.f);
        }
        __syncthreads();                                   // B7

        // ---- window W4: waves 0-5 fc(t); waves 6-15 P1(t+1) ----
        if (wid < 6) {
            f32x4 facc = {0.f, 0.f, 0.f, 0.f};
            const f16* __restrict__ Af = &hbufh[pb ^ 1][arow4][khi * 8];
            const f16* __restrict__ Bf = WFCM + wid * 4096 + lane * 8;
            #pragma unroll 2
            for (int kw = 0; kw < 8; ++kw) {
                const f16x8 a = *(const f16x8*)(Af + kw * 32);
                const f16x8 b = *(const f16x8*)(Bf + kw * 512);
                facc = __builtin_amdgcn_mfma_f32_16x16x32_f16(a, b, facc, 0, 0, 0);
            }
            if (lane < 16) {
                const int col = wid * 16 + mrow;
                if (col < NV) {
                    #pragma unroll
                    for (int i = 0; i < 4; ++i) lg_s[i][col] = facc[i] + bfc_s[col];
                }
            }
        } else {
            // P1(t+1): waves 6-15, 2 ntiles each (20 total), A = h(t+1) f16
            const int na = (wid - 6) * 2;
            f32x4 za0 = {0.f, 0.f, 0.f, 0.f}, za1 = {0.f, 0.f, 0.f, 0.f};
            const f16* __restrict__ B0 = WATTM + na * 4096 + lane * 8;
            const f16* __restrict__ B1 = WATTM + (na + 1) * 4096 + lane * 8;
            const f16* __restrict__ hr = &hbufh[pb ^ 1][arow4][khi * 8];
            #pragma unroll 2
            for (int kw = 0; kw < 8; ++kw) {
                const f16x8 a = *(const f16x8*)(hr + kw * 32);
                za0 = __builtin_amdgcn_mfma_f32_16x16x32_f16(a, *(const f16x8*)(B0 + kw * 512), za0, 0, 0, 0);
                za1 = __builtin_amdgcn_mfma_f32_16x16x32_f16(a, *(const f16x8*)(B1 + kw * 512), za1, 0, 0, 0);
            }
            if (lane < 16) {
                #pragma unroll
                for (int i = 0; i < 4; ++i) {
                    p_s[i][na * 16 + mrow]       = za0[i];
                    p_s[i][(na + 1) * 16 + mrow] = za1[i];
                }
            }
        }
        __syncthreads();                                   // B8

        // ---- merged: out write + argmax + loss (waves 0-3, one row each) ----
        if (wid < 4) {
            const int rr = wid;
            float* __restrict__ outr = out_logits + ((size_t)t * NB + row0 + rr) * NV;
            const float lv1 = lg_s[rr][lane];
            outr[lane] = lv1;
            float v0 = lv1; int i0 = lane;
            float lv2 = -3.4e38f;
            if (lane < NV - 64) {
                const int v2 = 64 + lane;
                lv2 = lg_s[rr][v2];
                outr[v2] = lv2;
                if (lv2 > v0) { v0 = lv2; i0 = v2; }
            }
            #pragma unroll
            for (int off = 32; off > 0; off >>= 1) {
                const float vo = __shfl_xor(v0, off);
                const int   io = __shfl_xor(i0, off);
                if (vo > v0 || (vo == v0 && io < i0)) { v0 = vo; i0 = io; }
            }
            float e = __expf(lv1 - v0);
            if (lane < NV - 64) e += __expf(lv2 - v0);
            #pragma unroll
            for (int off = 32; off > 0; off >>= 1) e += __shfl_xor(e, off);
            if (lane == 0) {
                const int y = tgt[(row0 + rr) * NT + t];
                loss_s[rr] += -(lg_s[rr][y] - v0 - logf(e));
                xd_s[rr] = i0;
            }
        }
        // no trailing barrier: p_s(t+1) ordered by B8; xd_s/lg_s/loss_s self-consumed by waves 0-3;
        // waves 4-15 flow into next W2's gates h-half (hb8 ordered by B7).
    }

    __syncthreads();
    if (tid < 4) loss_out[row0 + tid] = loss_s[tid];
}

// ---------------- final mean ----------------
__global__ __launch_bounds__(256) void k_final(const float* __restrict__ loss, float* __restrict__ dst) {
    const int tid = threadIdx.x;
    float v = loss[tid] + loss[tid + 256] + loss[tid + 512] + loss[tid + 768];
    #pragma unroll
    for (int o = 32; o > 0; o >>= 1) v += __shfl_xor(v, o);
    __shared__ float red[4];
    if ((tid & 63) == 0) red[tid >> 6] = v;
    __syncthreads();
    if (tid == 0) dst[0] = (red[0] + red[1] + red[2] + red[3]) / (float)(NB * NT);
}

extern "C" void kernel_launch(void* const* d_in, const int* in_sizes, int n_in,
                              void* d_out, int out_size, void* d_ws, size_t ws_size,
                              hipStream_t stream) {
    const int*   enc    = (const int*)d_in[0];
    const int*   tgt    = (const int*)d_in[1];
    const float* emb    = (const float*)d_in[3];
    const float* W_att  = (const float*)d_in[4];
    const float* b_att  = (const float*)d_in[5];
    const float* W_comb = (const float*)d_in[6];
    const float* b_comb = (const float*)d_in[7];
    const float* W_ih   = (const float*)d_in[8];
    const float* b_ih   = (const float*)d_in[9];
    const float* W_hh   = (const float*)d_in[10];
    const float* b_hh   = (const float*)d_in[11];
    const float* W_fc   = (const float*)d_in[12];
    const float* b_fc   = (const float*)d_in[13];

    float* ws  = (float*)d_ws;
    float* out = (float*)d_out;
    unsigned char* WCAT8 = (unsigned char*)(ws + OFF_WCAT8);
    f16* WATTM = (f16*)(ws + OFF_WATTM);
    f16* WFCM  = (f16*)(ws + OFF_WFCM);
    f16* Q2TM  = (f16*)(ws + OFF_Q2TM);

    hipLaunchKernelGGL(k_pe,      dim3(1),    dim3(128), 0, stream, ws + OFF_PE);
    hipLaunchKernelGGL(k_tr_att,  dim3(640),  dim3(256), 0, stream, W_att,  ws + OFF_WATT);
    hipLaunchKernelGGL(k_tr_comb, dim3(512),  dim3(256), 0, stream, W_comb, ws + OFF_WCOMBT);
    hipLaunchKernelGGL(k_p1b,     dim3(81),   dim3(320), 0, stream, emb, ws + OFF_WATT, b_att, ws + OFF_P1B);
    hipLaunchKernelGGL(k_p2q,     dim3(81),   dim3(256), 0, stream, emb, ws + OFF_WCOMBT, b_comb,
                       ws + OFF_P2B, ws + OFF_Q2T);
    hipLaunchKernelGGL(k_q2pe,    dim3(1),    dim3(256), 0, stream, ws + OFF_PE, ws + OFF_WCOMBT, ws + OFF_Q2PE);
    hipLaunchKernelGGL(k_pan_q2m, dim3(96),   dim3(256), 0, stream, ws + OFF_Q2T, Q2TM);
    hipLaunchKernelGGL(k_pan_cat_8, dim3(2048), dim3(256), 0, stream, W_ih, W_hh, WCAT8);
    hipLaunchKernelGGL(k_pan_att_m, dim3(320),  dim3(256), 0, stream, W_att, WATTM);
    hipLaunchKernelGGL(k_pan_fc_m,  dim3(96),   dim3(256), 0, stream, W_fc, WFCM);

    hipLaunchKernelGGL(k_run, dim3(256), dim3(1024), 0, stream,
                       enc, tgt,
                       WATTM, ws + OFF_P1B, ws + OFF_P2B,
                       Q2TM, ws + OFF_Q2PE, WCAT8, WFCM,
                       b_ih, b_hh, b_fc,
                       out, ws + OFF_LOSS);

    hipLaunchKernelGGL(k_final, dim3(1), dim3(256), 0, stream, ws + OFF_LOSS, out + (out_size - 1));
}

// Round 23
// 1708.041 us; speedup vs baseline: 2.1741x; 2.1741x over previous
//
#include <hip/hip_runtime.h>
#include <hip/hip_fp8.h>

#define NB 1024
#define SL 300
#define NT 150
#define NH 256
#define LA 320
#define NV 81
#define HST 272   // f16 row stride in halves: 136 words ≡ 8 (mod 32)
#define BST 288   // fp8 row stride in bytes: 72 words ≡ 8 (mod 32)

typedef _Float16 f16;
typedef _Float16 f16x2 __attribute__((ext_vector_type(2)));
typedef _Float16 f16x8 __attribute__((ext_vector_type(8)));
typedef float    f32x4 __attribute__((ext_vector_type(4)));

// ws float offsets (bytes-vs-floats audited)
#define OFF_WATT    0u         // [512][320] f32 (163840)
#define OFF_WCOMBT  163840u    // [512][256] f32 (131072)
#define OFF_P1B     294912u    // [81][320] f32 (25920)
#define OFF_P2B     320832u    // [81][256] f32 (20736)
#define OFF_Q2T     341568u    // [81][256] f32 intermediate (20736)
#define OFF_Q2PE    362304u    // [256]
#define OFF_PE      362560u    // [256]
#define OFF_Q2TM    362816u    // f16 frags [16 nt][3 kw][64][8] = 24576 halves (12288 floats)
#define OFF_WCAT8   375104u    // fp8 frags [64 nt][16 kw][64][8] = 524288 B (131072 floats)
#define OFF_WATTM   506176u    // f16 frags [20 nt][8 kw][64][8] = 81920 halves (40960 floats)
#define OFF_WFCM    547136u    // f16 frags [6 nt][8 kw][64][8] = 24576 halves (12288 floats)
#define OFF_LOSS    559424u    // [1024]

static __device__ __forceinline__ float rcpf(float x)  { return __builtin_amdgcn_rcpf(x); }
static __device__ __forceinline__ float sigm(float x)  { return rcpf(1.f + __expf(-x)); }
static __device__ __forceinline__ float tanhf_(float x){ return 1.f - 2.f * rcpf(1.f + __expf(2.f * x)); }

static __device__ __forceinline__ unsigned char f2fp8(float x) {
#if __has_builtin(__builtin_amdgcn_cvt_pk_fp8_f32)
    return (unsigned char)(__builtin_amdgcn_cvt_pk_fp8_f32(x, 0.f, 0, false) & 0xff);
#else
    __hip_fp8_e4m3 t(x);
    return (unsigned char)t.__x;
#endif
}

// ---------------- setup kernels ----------------
__global__ __launch_bounds__(128) void k_pe(float* __restrict__ pe) {
    const int i = threadIdx.x;
    const float arg  = (float)(2 * i) * (-0.035977892078031968f);
    const float divf = expf(arg) * 300.0f;
    pe[2 * i]     = (float)sin((double)divf);
    pe[2 * i + 1] = (float)cos((double)divf);
}
__global__ __launch_bounds__(256) void k_tr_att(const float* __restrict__ W, float* __restrict__ WT) {
    const int i = blockIdx.x * 256 + threadIdx.x;
    if (i < 512 * LA) { const int k = i / LA, l = i - k * LA; WT[i] = W[l * 512 + k]; }
}
__global__ __launch_bounds__(256) void k_tr_comb(const float* __restrict__ W, float* __restrict__ WT) {
    const int i = blockIdx.x * 256 + threadIdx.x;
    const int k = i >> 8, j = i & 255;
    if (i < 512 * NH) WT[i] = W[j * 512 + k];
}
__global__ __launch_bounds__(320) void k_p1b(const float* __restrict__ emb, const float* __restrict__ WATT,
                                             const float* __restrict__ b_att, float* __restrict__ P1B) {
    __shared__ float e[NH];
    const int v = blockIdx.x, tid = threadIdx.x;
    if (tid < NH) e[tid] = emb[v * NH + tid];
    __syncthreads();
    float a = b_att[tid];
    #pragma unroll 8
    for (int k = 0; k < NH; ++k) a += e[k] * WATT[k * LA + tid];
    P1B[v * LA + tid] = a;
}
__global__ __launch_bounds__(256) void k_p2q(const float* __restrict__ emb, const float* __restrict__ WCOMBT,
                                             const float* __restrict__ b_comb,
                                             float* __restrict__ P2B, float* __restrict__ Q2T) {
    __shared__ float e[NH];
    const int v = blockIdx.x, tid = threadIdx.x;
    e[tid] = emb[v * NH + tid];
    __syncthreads();
    float a = b_comb[tid], q = 0.f;
    #pragma unroll 8
    for (int k = 0; k < NH; ++k) {
        a += e[k] * WCOMBT[k * NH + tid];
        q += e[k] * WCOMBT[(NH + k) * NH + tid];
    }
    P2B[v * NH + tid] = a;
    Q2T[v * NH + tid] = q;
}
__global__ __launch_bounds__(256) void k_q2pe(const float* __restrict__ pe, const float* __restrict__ WCOMBT,
                                              float* __restrict__ Q2PE) {
    __shared__ float e[NH];
    const int tid = threadIdx.x;
    e[tid] = pe[tid];
    __syncthreads();
    float q = 0.f;
    #pragma unroll 8
    for (int k = 0; k < NH; ++k) q += e[k] * WCOMBT[(NH + k) * NH + tid];
    Q2PE[tid] = q;
}
// Q2T -> f16 MFMA B-frags: B[k=v (pad 96)][col=j]
__global__ __launch_bounds__(256) void k_pan_q2m(const float* __restrict__ Q2T, f16* __restrict__ P) {
    const int i = blockIdx.x * 256 + threadIdx.x;
    if (i < 96 * 256) {
        const int v = i >> 8, j = i & 255;
        const float val = (v < NV) ? Q2T[v * NH + j] : 0.f;
        const int nt = j >> 4, kw = v >> 5, kr = v & 31;
        const int l = (kr >> 3) * 16 + (j & 15), jj = kr & 7;
        P[nt * 1536 + kw * 512 + l * 8 + jj] = (f16)val;
    }
}
// gates weights -> fp8 MFMA B-frags, stored e4m3(64*w)
__global__ __launch_bounds__(256) void k_pan_cat_8(const float* __restrict__ Wih, const float* __restrict__ Whh,
                                                   unsigned char* __restrict__ P) {
    const int i = blockIdx.x * 256 + threadIdx.x;
    if (i < 512 * 1024) {
        const int k = i >> 10, c = i & 1023, jcol = c >> 2, g = c & 3;
        const float v = (k < NH) ? Wih[(g * NH + jcol) * NH + k] : Whh[(g * NH + jcol) * NH + (k - NH)];
        const int nt = c >> 4, kw = k >> 5, kr = k & 31;
        const int l = (kr >> 3) * 16 + (c & 15), jj = kr & 7;
        P[nt * 8192 + kw * 512 + l * 8 + jj] = f2fp8(v * 64.f);
    }
}
// attn-h weights -> f16 MFMA B-frags
__global__ __launch_bounds__(256) void k_pan_att_m(const float* __restrict__ W, f16* __restrict__ P) {
    const int i = blockIdx.x * 256 + threadIdx.x;
    if (i < 256 * LA) {
        const int k = i / LA, lcol = i - k * LA;
        const float v = W[lcol * 512 + 256 + k];
        const int nt = lcol >> 4, kw = k >> 5, kr = k & 31;
        const int l = (kr >> 3) * 16 + (lcol & 15), jj = kr & 7;
        P[nt * 4096 + kw * 512 + l * 8 + jj] = (f16)v;
    }
}
// W_fc -> f16 MFMA B-frags (pad 81->96 cols)
__global__ __launch_bounds__(256) void k_pan_fc_m(const float* __restrict__ W, f16* __restrict__ P) {
    const int i = blockIdx.x * 256 + threadIdx.x;
    if (i < 256 * 96) {
        const int k = i / 96, v = i - k * 96;
        const float val = (v < NV) ? W[v * NH + k] : 0.f;
        const int nt = v >> 4, kw = k >> 5, kr = k & 31;
        const int l = (kr >> 3) * 16 + (v & 15), jj = kr & 7;
        P[nt * 4096 + kw * 512 + l * 8 + jj] = (f16)val;
    }
}

// ---------------- persistent decoder: 256 blocks x 1024 threads, 4 rows/block ----------------
__global__ __launch_bounds__(1024, 4) void k_run(
    const int* __restrict__ enc, const int* __restrict__ tgt,
    const f16* __restrict__ WATTM, const float* __restrict__ P1B,
    const float* __restrict__ P2B, const f16* __restrict__ Q2TM,
    const float* __restrict__ Q2PE, const unsigned char* __restrict__ WCAT8,
    const f16* __restrict__ WFCM,
    const float* __restrict__ bih, const float* __restrict__ bhh,
    const float* __restrict__ bfc, float* __restrict__ out_logits,
    float* __restrict__ loss_out)
{
    __shared__ __attribute__((aligned(16))) f16 hbufh[2][4][HST];
    __shared__ __attribute__((aligned(16))) unsigned char hb8[2][4][BST];
    __shared__ __attribute__((aligned(16))) unsigned char xh8[4][BST];
    __shared__ __attribute__((aligned(16))) f16 q2m_lds[16 * 1536];   // 48 KB
    __shared__ __attribute__((aligned(16))) f16 cwh[4][96];
    __shared__ float q2pe_lds[NH];
    __shared__ float p_s[4][324];
    __shared__ float gex[4][1024];
    __shared__ float bsum_lds[1024];
    __shared__ float lg_s[4][96];
    __shared__ unsigned short idx16[4][SL];
    __shared__ unsigned short cnt16[4][NV];
    __shared__ unsigned short offs16[4][NV + 1];
    __shared__ float sm_inv[4], sm_s300[4];
    __shared__ float bfc_s[96];
    __shared__ float loss_s[4];
    __shared__ int   xd_s[4];

    const int tid  = threadIdx.x;
    const int rowg = tid >> 8;
    const int jg   = tid & 255;
    const int wid  = tid >> 6;
    const int lane = tid & 63;
    const int mrow = lane & 15;
    const int arow4 = mrow & 3;
    const int khi  = lane >> 4;
    const int row0 = blockIdx.x * 4;
    // gates ntile assignment: waves 0-3 -> 1 nt (= wid); waves 4-15 -> 5 nt from nt0g
    const int nt0g = (wid < 4) ? wid : (4 + (wid - 4) * 5);

    // ---- init ----
    {
        f16* hz = &hbufh[0][0][0];
        for (int i = tid; i < 2 * 4 * HST; i += 1024) hz[i] = (f16)0.f;
        unsigned char* h8 = &hb8[0][0][0];
        for (int i = tid; i < 2 * 4 * BST; i += 1024) h8[i] = 0;
        unsigned char* x8 = &xh8[0][0];
        for (int i = tid; i < 4 * BST; i += 1024) x8[i] = 0;
    }
    { const int j = tid >> 2, g = tid & 3; bsum_lds[tid] = bih[g * NH + j] + bhh[g * NH + j]; }
    if (tid < 96) bfc_s[tid] = (tid < NV) ? bfc[tid] : 0.f;
    if (tid < 4 * 96) cwh[tid / 96][tid % 96] = (f16)0.f;
    if (tid < 4) { xd_s[tid] = 1; loss_s[tid] = 0.f; }
    for (int i = tid; i < 3072; i += 1024)
        ((f16x8*)q2m_lds)[i] = ((const f16x8*)Q2TM)[i];
    if (tid < NH) q2pe_lds[tid] = Q2PE[tid];
    const int* __restrict__ encr = enc + (row0 + rowg) * SL;
    if (jg < NV) {
        int c = 0;
        for (int l = 0; l < SL; ++l) c += (encr[l] == jg);
        cnt16[rowg][jg] = (unsigned short)c;
    }
    __syncthreads();
    if (jg == 0) {
        int o = 0; offs16[rowg][0] = 0;
        for (int v = 0; v < NV; ++v) { o += cnt16[rowg][v]; offs16[rowg][v + 1] = (unsigned short)o; }
    }
    __syncthreads();
    if (jg < NV) {
        int o = offs16[rowg][jg];
        for (int l = 0; l < SL; ++l) if (encr[l] == jg) idx16[rowg][o++] = (unsigned short)l;
    }
    __syncthreads();

    // ---- prologue: P1(0) on all 16 waves (h = 0) ----
    {
        f32x4 za0 = {0.f, 0.f, 0.f, 0.f}, za1 = {0.f, 0.f, 0.f, 0.f};
        const bool two = (wid < 4);
        const f16* __restrict__ B0 = WATTM + wid * 4096 + lane * 8;
        const f16* __restrict__ B1 = WATTM + (16 + wid) * 4096 + lane * 8;
        const f16* __restrict__ hr = &hbufh[0][arow4][khi * 8];
        #pragma unroll 4
        for (int kw = 0; kw < 8; ++kw) {
            const f16x8 a = *(const f16x8*)(hr + kw * 32);
            za0 = __builtin_amdgcn_mfma_f32_16x16x32_f16(a, *(const f16x8*)(B0 + kw * 512), za0, 0, 0, 0);
            if (two)
                za1 = __builtin_amdgcn_mfma_f32_16x16x32_f16(a, *(const f16x8*)(B1 + kw * 512), za1, 0, 0, 0);
        }
        if (lane < 16) {
            #pragma unroll
            for (int i = 0; i < 4; ++i) p_s[i][wid * 16 + mrow] = za0[i];
            if (two) {
                #pragma unroll
                for (int i = 0; i < 4; ++i) p_s[i][256 + wid * 16 + mrow] = za1[i];
            }
        }
    }
    __syncthreads();

    float creg = 0.f;   // cell state for (rowg, jg)

    for (int t = 0; t < NT; ++t) {
        const int pb = t & 1;
        f32x4 gacc[5];
        #pragma unroll
        for (int n = 0; n < 5; ++n) gacc[n] = (f32x4){0.f, 0.f, 0.f, 0.f};

        // ---- window W2: waves 0-3 softmax+binning(t); waves 4-15 gates h-half(t) ----
        if (wid < 4) {
            const int r = wid;
            const float* __restrict__ P1r = P1B + xd_s[r] * LA;
            float zv[5];
            #pragma unroll
            for (int i = 0; i < 5; ++i) zv[i] = p_s[r][lane + 64 * i] + P1r[lane + 64 * i];
            float m = fmaxf(fmaxf(fmaxf(zv[0], zv[1]), fmaxf(zv[2], zv[3])), zv[4]);
            #pragma unroll
            for (int off = 32; off > 0; off >>= 1) m = fmaxf(m, __shfl_xor(m, off));
            float sa = 0.f;
            #pragma unroll
            for (int i = 0; i < 5; ++i) {
                zv[i] = __expf(zv[i] - m);
                p_s[r][lane + 64 * i] = zv[i];
                sa += zv[i];
            }
            float sh = (lane >= 44) ? zv[4] : 0.f;         // l in [300,320)
            #pragma unroll
            for (int off = 32; off > 0; off >>= 1) { sa += __shfl_xor(sa, off); sh += __shfl_xor(sh, off); }
            {   // bins 0..63
                const int o0 = offs16[r][lane], o1 = offs16[r][lane + 1];
                float s = 0.f;
                for (int o = o0; o < o1; ++o) s += p_s[r][idx16[r][o]];
                cwh[r][lane] = (f16)s;
            }
            if (lane < NV - 64) {   // bins 64..80
                const int b2 = 64 + lane;
                const int o0 = offs16[r][b2], o1 = offs16[r][b2 + 1];
                float s = 0.f;
                for (int o = o0; o < o1; ++o) s += p_s[r][idx16[r][o]];
                cwh[r][b2] = (f16)s;
            }
            if (lane == 0) { sm_inv[r] = 1.0f / sa; sm_s300[r] = sa - sh; }
        } else {
            // gates h-half: 5 ntiles, kw 8..15 (A = h(t) fp8, ready since t-1's B7)
            const unsigned char* __restrict__ BG = WCAT8 + (size_t)nt0g * 8192 + lane * 8;
            const unsigned char* __restrict__ hr8 = &hb8[pb][arow4][khi * 8];
            #pragma unroll 2
            for (int kw = 8; kw < 16; ++kw) {
                const long a = *(const long*)(hr8 + (kw - 8) * 32);
                const unsigned char* bp = BG + kw * 512;
                #pragma unroll
                for (int n = 0; n < 5; ++n)
                    gacc[n] = __builtin_amdgcn_mfma_f32_16x16x32_fp8_fp8(
                        a, *(const long*)(bp + (size_t)n * 8192), gacc[n], 0, 0, 0);
            }
        }
        __syncthreads();                                   // B3

        // ---- phase 2: x via MFMA (wave = 1 ntile of 16 cols; K=96) + epilogue ----
        {
            f32x4 xacc = {0.f, 0.f, 0.f, 0.f};
            const f16* __restrict__ Aq = &cwh[arow4][khi * 8];
            const f16* __restrict__ Bq = q2m_lds + wid * 1536 + lane * 8;
            #pragma unroll
            for (int kw = 0; kw < 3; ++kw) {
                const f16x8 a = *(const f16x8*)(Aq + kw * 32);
                const f16x8 b = *(const f16x8*)(Bq + kw * 512);
                xacc = __builtin_amdgcn_mfma_f32_16x16x32_f16(a, b, xacc, 0, 0, 0);
            }
            if (lane < 16) {
                const int col = wid * 16 + mrow;
                #pragma unroll
                for (int i = 0; i < 4; ++i) {
                    const float xval = fmaxf(P2B[xd_s[i] * NH + col]
                                             + (xacc[i] + sm_s300[i] * q2pe_lds[col]) * sm_inv[i], 0.f);
                    xh8[i][col] = f2fp8(xval * 16.f);
                }
            }
        }
        __syncthreads();                                   // B5

        // ---- phase 3: gates completion ----
        if (wid < 4) {
            const unsigned char* __restrict__ BG = WCAT8 + (size_t)nt0g * 8192 + lane * 8;
            const unsigned char* __restrict__ xr8 = &xh8[arow4][khi * 8];
            const unsigned char* __restrict__ hr8 = &hb8[pb][arow4][khi * 8];
            #pragma unroll 4
            for (int kw = 0; kw < 16; ++kw) {
                const long a = (kw < 8) ? *(const long*)(xr8 + kw * 32)
                                        : *(const long*)(hr8 + (kw - 8) * 32);
                gacc[0] = __builtin_amdgcn_mfma_f32_16x16x32_fp8_fp8(
                    a, *(const long*)(BG + kw * 512), gacc[0], 0, 0, 0);
            }
            if (lane < 16) {
                const int cc = nt0g * 16 + mrow;
                #pragma unroll
                for (int i = 0; i < 4; ++i) gex[i][cc] = gacc[0][i] * 0.0009765625f;
            }
        } else {
            const unsigned char* __restrict__ BG = WCAT8 + (size_t)nt0g * 8192 + lane * 8;
            const unsigned char* __restrict__ xr8 = &xh8[arow4][khi * 8];
            #pragma unroll 2
            for (int kw = 0; kw < 8; ++kw) {
                const long a = *(const long*)(xr8 + kw * 32);
                const unsigned char* bp = BG + kw * 512;
                #pragma unroll
                for (int n = 0; n < 5; ++n)
                    gacc[n] = __builtin_amdgcn_mfma_f32_16x16x32_fp8_fp8(
                        a, *(const long*)(bp + (size_t)n * 8192), gacc[n], 0, 0, 0);
            }
            if (lane < 16) {
                #pragma unroll
                for (int n = 0; n < 5; ++n) {
                    const int cc = (nt0g + n) * 16 + mrow;
                    #pragma unroll
                    for (int i = 0; i < 4; ++i) gex[i][cc] = gacc[n][i] * 0.0009765625f;
                }
            }
        }
        __syncthreads();                                   // B6

        // ---- LSTM pointwise (adds bias); writes h f16 + fp8 ----
        {
            const float4 g4 = *(const float4*)(gex[rowg] + 4 * jg);   // i,f,g,o
            const float4 b4 = *(const float4*)(bsum_lds + 4 * jg);
            creg = sigm(g4.y + b4.y) * creg + sigm(g4.x + b4.x) * tanhf_(g4.z + b4.z);
            const float hv = sigm(g4.w + b4.w) * tanhf_(creg);
            hbufh[pb ^ 1][rowg][jg] = (f16)hv;
            hb8[pb ^ 1][rowg][jg] = f2fp8(hv * 16.f);
        }
        __syncthreads();                                   // B7

        // ---- window W4: waves 0-5 fc(t); waves 6-15 P1(t+1) ----
        if (wid < 6) {
            f32x4 facc = {0.f, 0.f, 0.f, 0.f};
            const f16* __restrict__ Af = &hbufh[pb ^ 1][arow4][khi * 8];
            const f16* __restrict__ Bf = WFCM + wid * 4096 + lane * 8;
            #pragma unroll 2
            for (int kw = 0; kw < 8; ++kw) {
                const f16x8 a = *(const f16x8*)(Af + kw * 32);
                const f16x8 b = *(const f16x8*)(Bf + kw * 512);
                facc = __builtin_amdgcn_mfma_f32_16x16x32_f16(a, b, facc, 0, 0, 0);
            }
            if (lane < 16) {
                const int col = wid * 16 + mrow;
                if (col < NV) {
                    #pragma unroll
                    for (int i = 0; i < 4; ++i) lg_s[i][col] = facc[i] + bfc_s[col];
                }
            }
        } else {
            // P1(t+1): waves 6-15, 2 ntiles each (20 total), A = h(t+1) f16
            const int na = (wid - 6) * 2;
            f32x4 za0 = {0.f, 0.f, 0.f, 0.f}, za1 = {0.f, 0.f, 0.f, 0.f};
            const f16* __restrict__ B0 = WATTM + na * 4096 + lane * 8;
            const f16* __restrict__ B1 = WATTM + (na + 1) * 4096 + lane * 8;
            const f16* __restrict__ hr = &hbufh[pb ^ 1][arow4][khi * 8];
            #pragma unroll 2
            for (int kw = 0; kw < 8; ++kw) {
                const f16x8 a = *(const f16x8*)(hr + kw * 32);
                za0 = __builtin_amdgcn_mfma_f32_16x16x32_f16(a, *(const f16x8*)(B0 + kw * 512), za0, 0, 0, 0);
                za1 = __builtin_amdgcn_mfma_f32_16x16x32_f16(a, *(const f16x8*)(B1 + kw * 512), za1, 0, 0, 0);
            }
            if (lane < 16) {
                #pragma unroll
                for (int i = 0; i < 4; ++i) {
                    p_s[i][na * 16 + mrow]       = za0[i];
                    p_s[i][(na + 1) * 16 + mrow] = za1[i];
                }
            }
        }
        __syncthreads();                                   // B8

        // ---- merged: out write + argmax + loss (waves 0-3, one row each) ----
        if (wid < 4) {
            const int rr = wid;
            float* __restrict__ outr = out_logits + ((size_t)t * NB + row0 + rr) * NV;
            const float lv1 = lg_s[rr][lane];
            outr[lane] = lv1;
            float v0 = lv1; int i0 = lane;
            float lv2 = -3.4e38f;
            if (lane < NV - 64) {
                const int v2 = 64 + lane;
                lv2 = lg_s[rr][v2];
                outr[v2] = lv2;
                if (lv2 > v0) { v0 = lv2; i0 = v2; }
            }
            #pragma unroll
            for (int off = 32; off > 0; off >>= 1) {
                const float vo = __shfl_xor(v0, off);
                const int   io = __shfl_xor(i0, off);
                if (vo > v0 || (vo == v0 && io < i0)) { v0 = vo; i0 = io; }
            }
            float e = __expf(lv1 - v0);
            if (lane < NV - 64) e += __expf(lv2 - v0);
            #pragma unroll
            for (int off = 32; off > 0; off >>= 1) e += __shfl_xor(e, off);
            if (lane == 0) {
                const int y = tgt[(row0 + rr) * NT + t];
                loss_s[rr] += -(lg_s[rr][y] - v0 - logf(e));
                xd_s[rr] = i0;
            }
        }
        // no trailing barrier: p_s(t+1) ordered by B8; xd_s/lg_s/loss_s self-consumed by waves 0-3;
        // waves 4-15 flow into next W2's gates h-half (hb8 ordered by B7).
    }

    __syncthreads();
    if (tid < 4) loss_out[row0 + tid] = loss_s[tid];
}

// ---------------- final mean ----------------
__global__ __launch_bounds__(256) void k_final(const float* __restrict__ loss, float* __restrict__ dst) {
    const int tid = threadIdx.x;
    float v = loss[tid] + loss[tid + 256] + loss[tid + 512] + loss[tid + 768];
    #pragma unroll
    for (int o = 32; o > 0; o >>= 1) v += __shfl_xor(v, o);
    __shared__ float red[4];
    if ((tid & 63) == 0) red[tid >> 6] = v;
    __syncthreads();
    if (tid == 0) dst[0] = (red[0] + red[1] + red[2] + red[3]) / (float)(NB * NT);
}

extern "C" void kernel_launch(void* const* d_in, const int* in_sizes, int n_in,
                              void* d_out, int out_size, void* d_ws, size_t ws_size,
                              hipStream_t stream) {
    const int*   enc    = (const int*)d_in[0];
    const int*   tgt    = (const int*)d_in[1];
    const float* emb    = (const float*)d_in[3];
    const float* W_att  = (const float*)d_in[4];
    const float* b_att  = (const float*)d_in[5];
    const float* W_comb = (const float*)d_in[6];
    const float* b_comb = (const float*)d_in[7];
    const float* W_ih   = (const float*)d_in[8];
    const float* b_ih   = (const float*)d_in[9];
    const float* W_hh   = (const float*)d_in[10];
    const float* b_hh   = (const float*)d_in[11];
    const float* W_fc   = (const float*)d_in[12];
    const float* b_fc   = (const float*)d_in[13];

    float* ws  = (float*)d_ws;
    float* out = (float*)d_out;
    unsigned char* WCAT8 = (unsigned char*)(ws + OFF_WCAT8);
    f16* WATTM = (f16*)(ws + OFF_WATTM);
    f16* WFCM  = (f16*)(ws + OFF_WFCM);
    f16* Q2TM  = (f16*)(ws + OFF_Q2TM);

    hipLaunchKernelGGL(k_pe,      dim3(1),    dim3(128), 0, stream, ws + OFF_PE);
    hipLaunchKernelGGL(k_tr_att,  dim3(640),  dim3(256), 0, stream, W_att,  ws + OFF_WATT);
    hipLaunchKernelGGL(k_tr_comb, dim3(512),  dim3(256), 0, stream, W_comb, ws + OFF_WCOMBT);
    hipLaunchKernelGGL(k_p1b,     dim3(81),   dim3(320), 0, stream, emb, ws + OFF_WATT, b_att, ws + OFF_P1B);
    hipLaunchKernelGGL(k_p2q,     dim3(81),   dim3(256), 0, stream, emb, ws + OFF_WCOMBT, b_comb,
                       ws + OFF_P2B, ws + OFF_Q2T);
    hipLaunchKernelGGL(k_q2pe,    dim3(1),    dim3(256), 0, stream, ws + OFF_PE, ws + OFF_WCOMBT, ws + OFF_Q2PE);
    hipLaunchKernelGGL(k_pan_q2m, dim3(96),   dim3(256), 0, stream, ws + OFF_Q2T, Q2TM);
    hipLaunchKernelGGL(k_pan_cat_8, dim3(2048), dim3(256), 0, stream, W_ih, W_hh, WCAT8);
    hipLaunchKernelGGL(k_pan_att_m, dim3(320),  dim3(256), 0, stream, W_att, WATTM);
    hipLaunchKernelGGL(k_pan_fc_m,  dim3(96),   dim3(256), 0, stream, W_fc, WFCM);

    hipLaunchKernelGGL(k_run, dim3(256), dim3(1024), 0, stream,
                       enc, tgt,
                       WATTM, ws + OFF_P1B, ws + OFF_P2B,
                       Q2TM, ws + OFF_Q2PE, WCAT8, WFCM,
                       b_ih, b_hh, b_fc,
                       out, ws + OFF_LOSS);

    hipLaunchKernelGGL(k_final, dim3(1), dim3(256), 0, stream, ws + OFF_LOSS, out + (out_size - 1));
}